// Round 7
// baseline (97.265 us; speedup 1.0000x reference)
//
#include <hip/hip_runtime.h>

#define NTYPES 50
#define NCATS  20
#define EDIM   64
#define BATCH  4
#define SEQL   256

// Blocks: 512 LL (b, pair{pr, 255-pr}) + 200 IT (b,t) + 4 IC (b) + 1 I0
#define LL_BLOCKS 512
#define IT_BLOCKS 200
#define IC_BLOCKS 4
#define TOTAL_BLOCKS 717

// ws float layout, every slot/counter on its own 128B (32-float) line:
//   value slot (target, g) at ws[(target*16+g)*32]; targets: 0=ll, 1..4=int_b, 5=I0
//   sub-counter g at ws[(96+g)*32]; top counter at ws[112*32]
#define SLOT(tgt, g) (((tgt) * 16 + (g)) * 32)
#define SUBC(g)      ((96 + (g)) * 32)
#define TOPC         (112 * 32)
#define WS_ZERO_BYTES ((112 * 32 + 1) * 4)

__device__ __forceinline__ float softplusf(float x) {
    return (x > 0.f) ? x + log1pf(__expf(-x)) : log1pf(__expf(x));
}

__device__ __forceinline__ float waveReduceSum(float v) {
    #pragma unroll
    for (int off = 32; off > 0; off >>= 1) v += __shfl_down(v, off, 64);
    return v;
}

__global__ __launch_bounds__(256) void hawkes_fused(
        const float* __restrict__ times,
        const int*   __restrict__ types,
        const int*   __restrict__ cats,
        const int*   __restrict__ Tp,
        const float* __restrict__ type_emb,
        const float* __restrict__ cat_emb,
        const float* __restrict__ amat,
        const float* __restrict__ bmat,
        const float* __restrict__ A,
        const float* __restrict__ P,
        const float* __restrict__ Bm,
        const float* __restrict__ Q,
        float* __restrict__ ws,
        float* __restrict__ out) {
    const int blk  = blockIdx.x;
    const int tid  = threadIdx.x;
    const int lane = tid & 63;
    const int wave = tid >> 6;
    const int e2   = lane & 31;   // float2 index over embedding dim
    const int sub  = lane >> 5;   // which source this half-wave handles
    const int g    = blk & 15;

    __shared__ float2 sSeq[SEQL];          // (time, bitcast(type | cat<<16))
    __shared__ float  red1[4], red2[4];
    __shared__ float  sn[4][EDIM];
    __shared__ float  fin[96];
    __shared__ int    finflag;

    const float2* TE  = (const float2*)type_emb;  // row r at TE [r*32 + e2]
    const float2* CE  = (const float2*)cat_emb;
    const float2* A2p = (const float2*)A;
    const float2* P2p = (const float2*)P;
    const float2* B2p = (const float2*)Bm;
    const float2* Q2p = (const float2*)Q;
    const float2* am2 = (const float2*)amat;
    const float2* bm2 = (const float2*)bmat;

    if (blk < LL_BLOCKS) {
        // ---- two events per block: i1 = pr (0..127), i2 = 255-pr (128..255) ----
        const int b  = blk >> 7;
        const int pr = blk & 127;
        const int i1 = pr, i2 = 255 - pr;
        const int base = b * SEQL;
        for (int s = tid; s < SEQL; s += 256)
            sSeq[s] = make_float2(times[base + s],
                                  __int_as_float(types[base + s] | (cats[base + s] << 16)));
        __syncthreads();
        const int   t1  = __float_as_int(sSeq[i1].y) & 0xffff;
        const int   t2  = __float_as_int(sSeq[i2].y) & 0xffff;
        const int   c1  = (i1 > 0) ? (__float_as_int(sSeq[i1 - 1].y) >> 16) : 0;
        const int   c2  = __float_as_int(sSeq[i2 - 1].y) >> 16;
        const float ti1 = sSeq[i1].x, ti2 = sSeq[i2].x;
        const float2 te1 = TE[t1 * 32 + e2], te2 = TE[t2 * 32 + e2];
        const float2 ce1 = CE[c1 * 32 + e2], ce2 = CE[c2 * 32 + e2];

        float2 acc1 = make_float2(0.f, 0.f), acc2 = make_float2(0.f, 0.f);
        const int r = 2 * wave + sub;          // source residue mod 8
        // sources s < i1: feed both events
        #pragma unroll 2
        for (int s = r; s < i1; s += 8) {
            const float2 sq = sSeq[s];
            const int    tc = __float_as_int(sq.y);
            const int    k  = tc & 0xffff, cs = tc >> 16;
            const float  td1 = ti1 - sq.x, td2 = ti2 - sq.x;
            const float2 f   = TE[k * 32 + e2];
            const float2 gg  = CE[cs * 32 + e2];
            const float2 Av1 = A2p[(k * NTYPES + t1) * 32 + e2];
            const float2 Pv1 = P2p[(k * NTYPES + t1) * 32 + e2];
            const float2 Bv1 = B2p[(cs * NCATS + c1) * 32 + e2];
            const float2 Qv1 = Q2p[(cs * NCATS + c1) * 32 + e2];
            const float2 Av2 = A2p[(k * NTYPES + t2) * 32 + e2];
            const float2 Pv2 = P2p[(k * NTYPES + t2) * 32 + e2];
            const float2 Bv2 = B2p[(cs * NCATS + c2) * 32 + e2];
            const float2 Qv2 = Q2p[(cs * NCATS + c2) * 32 + e2];
            const float tfx1 = te1.x * f.x,  tfy1 = te1.y * f.y;
            const float cgx1 = ce1.x * gg.x, cgy1 = ce1.y * gg.y;
            const float tfx2 = te2.x * f.x,  tfy2 = te2.y * f.y;
            const float cgx2 = ce2.x * gg.x, cgy2 = ce2.y * gg.y;
            acc1.x += tfx1 * Av1.x * __expf(-tfx1 * Pv1.x * td1)
                    + cgx1 * Bv1.x * __expf(-cgx1 * Qv1.x * td1);
            acc1.y += tfy1 * Av1.y * __expf(-tfy1 * Pv1.y * td1)
                    + cgy1 * Bv1.y * __expf(-cgy1 * Qv1.y * td1);
            acc2.x += tfx2 * Av2.x * __expf(-tfx2 * Pv2.x * td2)
                    + cgx2 * Bv2.x * __expf(-cgx2 * Qv2.x * td2);
            acc2.y += tfy2 * Av2.y * __expf(-tfy2 * Pv2.y * td2)
                    + cgy2 * Bv2.y * __expf(-cgy2 * Qv2.y * td2);
        }
        // sources i1 <= s < i2: event2 only
        const int d  = i1 - r;
        const int s0 = r + ((d > 0) ? (((d + 7) >> 3) << 3) : 0);
        #pragma unroll 2
        for (int s = s0; s < i2; s += 8) {
            const float2 sq = sSeq[s];
            const int    tc = __float_as_int(sq.y);
            const int    k  = tc & 0xffff, cs = tc >> 16;
            const float  td2 = ti2 - sq.x;
            const float2 f   = TE[k * 32 + e2];
            const float2 gg  = CE[cs * 32 + e2];
            const float2 Av2 = A2p[(k * NTYPES + t2) * 32 + e2];
            const float2 Pv2 = P2p[(k * NTYPES + t2) * 32 + e2];
            const float2 Bv2 = B2p[(cs * NCATS + c2) * 32 + e2];
            const float2 Qv2 = Q2p[(cs * NCATS + c2) * 32 + e2];
            const float tfx2 = te2.x * f.x,  tfy2 = te2.y * f.y;
            const float cgx2 = ce2.x * gg.x, cgy2 = ce2.y * gg.y;
            acc2.x += tfx2 * Av2.x * __expf(-tfx2 * Pv2.x * td2)
                    + cgx2 * Bv2.x * __expf(-cgx2 * Qv2.x * td2);
            acc2.y += tfy2 * Av2.y * __expf(-tfy2 * Pv2.y * td2)
                    + cgy2 * Bv2.y * __expf(-cgy2 * Qv2.y * td2);
        }
        // base terms: added exactly once (sub==0 lanes cover all 64 e via float2)
        if (wave == 0 && sub == 0) {
            const float2 av = am2[t1 * 32 + e2];
            if (i1 == 0) {
                acc1.x += softplusf(te1.x * av.x);
                acc1.y += softplusf(te1.y * av.y);
            } else {
                const float2 bv = bm2[c1 * 32 + e2];
                acc1.x += te1.x * (av.x + bv.x);
                acc1.y += te1.y * (av.y + bv.y);
            }
        } else if (wave == 1 && sub == 0) {
            const float2 av = am2[t2 * 32 + e2];
            const float2 bv = bm2[c2 * 32 + e2];
            acc2.x += te2.x * (av.x + bv.x);
            acc2.y += te2.y * (av.y + bv.y);
        }
        const float r1 = waveReduceSum(acc1.x + acc1.y);
        const float r2 = waveReduceSum(acc2.x + acc2.y);
        if (lane == 0) { red1[wave] = r1; red2[wave] = r2; }
        __syncthreads();
        if (tid == 0) {
            const float lam1 = red1[0] + red1[1] + red1[2] + red1[3];
            const float lam2 = red2[0] + red2[1] + red2[2] + red2[3];
            atomicAdd(&ws[SLOT(0, g)], logf(lam1 + 1e-16f) + lam1
                                     + logf(lam2 + 1e-16f) + lam2);
        }
    } else if (blk < LL_BLOCKS + IT_BLOCKS) {
        // ---- horizon integral, type channel, (b, t) ----
        const int bt = blk - LL_BLOCKS;
        const int b = bt / NTYPES, t = bt % NTYPES;
        const int base = b * SEQL;
        for (int s = tid; s < SEQL; s += 256)
            sSeq[s] = make_float2(times[base + s], __int_as_float(types[base + s]));
        __syncthreads();
        const float  Tf = (float)Tp[0];
        const float2 te = TE[t * 32 + e2];
        float2 acc = make_float2(0.f, 0.f);
        const int r = 2 * wave + sub;
        #pragma unroll 4
        for (int s = r; s < SEQL; s += 8) {
            const float2 sq = sSeq[s];
            const int    k  = __float_as_int(sq.y);
            const float  td = Tf - sq.x;
            const float2 f  = TE[k * 32 + e2];
            const float2 Av = A2p[(k * NTYPES + t) * 32 + e2];
            const float2 Pv = P2p[(k * NTYPES + t) * 32 + e2];
            const float tfx = te.x * f.x, tfy = te.y * f.y;
            acc.x += tfx * Av.x * __expf(-tfx * Pv.x * td);
            acc.y += tfy * Av.y * __expf(-tfy * Pv.y * td);
        }
        const float rr = waveReduceSum(acc.x + acc.y);
        if (lane == 0) red1[wave] = rr;
        __syncthreads();
        if (tid == 0)
            atomicAdd(&ws[SLOT(1 + b, g)], red1[0] + red1[1] + red1[2] + red1[3]);
    } else if (blk < LL_BLOCKS + IT_BLOCKS + IC_BLOCKS) {
        // ---- horizon integral, category + base, per b (tiny; scalar form) ----
        const int b = blk - LL_BLOCKS - IT_BLOCKS;
        const int base = b * SEQL;
        const float Tf = (float)Tp[0];
        const int   lc = cats[base + SEQL - 1];
        const float ce = cat_emb[lc * EDIM + lane];
        float nacc = 0.f;
        #pragma unroll 4
        for (int s = wave; s < SEQL; s += 4) {
            const int   cs = cats[base + s];
            const float td = Tf - times[base + s];
            const float gg = cat_emb[cs * EDIM + lane];
            const float Bk = Bm[(cs * NCATS + lc) * EDIM + lane];
            const float Qk = Q [(cs * NCATS + lc) * EDIM + lane];
            const float cg = ce * gg;
            nacc += cg * Bk * __expf(-cg * Qk * td);
        }
        sn[wave][lane] = nacc;
        __syncthreads();
        if (wave == 0) {
            const float n_e = sn[0][lane] + sn[1][lane] + sn[2][lane] + sn[3][lane];
            float TA = 0.f, TS = 0.f;
            for (int t = 0; t < NTYPES; ++t) {
                const float tv = type_emb[t * EDIM + lane];
                TA += tv * amat[t * EDIM + lane];
                TS += tv;
            }
            float term = TA + (bmat[lc * EDIM + lane] + n_e) * TS;
            term = waveReduceSum(term);
            if (lane == 0) atomicAdd(&ws[SLOT(1 + b, g)], term);
        }
    } else {
        // ---- I0 ----
        float acc = 0.f;
        for (int t = wave; t < NTYPES; t += 4)
            acc += softplusf(type_emb[t * EDIM + lane] * amat[t * EDIM + lane]);
        const float rr = waveReduceSum(acc);
        if (lane == 0) red1[wave] = rr;
        __syncthreads();
        if (tid == 0)
            atomicAdd(&ws[SLOT(5, g)], red1[0] + red1[1] + red1[2] + red1[3]);
    }

    // ---- hierarchical completion; atomics-only coherence ----
    if (tid == 0) {
        finflag = 0;
        __asm__ __volatile__("s_waitcnt vmcnt(0)" ::: "memory");
        const unsigned cnt_g = (unsigned)((TOTAL_BLOCKS + 15 - g) >> 4);
        unsigned old = atomicAdd((unsigned int*)&ws[SUBC(g)], 1u);
        if (old == cnt_g - 1u) {
            unsigned o2 = atomicAdd((unsigned int*)&ws[TOPC], 1u);
            if (o2 == 15u) finflag = 1;
        }
    }
    __syncthreads();
    if (finflag) {
        if (tid < 96) fin[tid] = atomicAdd(&ws[tid * 32], 0.f);
        __syncthreads();
        if (tid == 0) {
            float ll = 0.f, i0 = 0.f;
            for (int j = 0; j < 16; ++j) { ll += fin[j]; i0 += fin[80 + j]; }
            const float Tf = (float)Tp[0];
            float tot = 0.f;
            for (int b2 = 0; b2 < BATCH; ++b2) {
                float ib = 0.f;
                for (int j = 0; j < 16; ++j) ib += fin[(1 + b2) * 16 + j];
                tot += ib * (Tf - times[b2 * SEQL + SEQL - 1]) + i0 * times[b2 * SEQL];
            }
            out[0] = -(ll - tot);
        }
    }
}

extern "C" void kernel_launch(void* const* d_in, const int* in_sizes, int n_in,
                              void* d_out, int out_size, void* d_ws, size_t ws_size,
                              hipStream_t stream) {
    const float* times    = (const float*)d_in[0];
    const int*   types    = (const int*)  d_in[1];
    const int*   cats     = (const int*)  d_in[2];
    const int*   Tp       = (const int*)  d_in[3];
    const float* type_emb = (const float*)d_in[4];
    const float* cat_emb  = (const float*)d_in[5];
    const float* amat     = (const float*)d_in[6];
    const float* bmat     = (const float*)d_in[7];
    const float* A        = (const float*)d_in[8];
    const float* P        = (const float*)d_in[9];
    const float* Bm       = (const float*)d_in[10];
    const float* Q        = (const float*)d_in[11];
    float* out = (float*)d_out;
    float* ws  = (float*)d_ws;

    hipMemsetAsync(ws, 0, WS_ZERO_BYTES, stream);

    hawkes_fused<<<TOTAL_BLOCKS, 256, 0, stream>>>(times, types, cats, Tp,
                                                   type_emb, cat_emb, amat, bmat,
                                                   A, P, Bm, Q, ws, out);
}